// Round 12
// baseline (299.319 us; speedup 1.0000x reference)
//
#include <hip/hip_runtime.h>
#include <hip/hip_bf16.h>

using short8 = __attribute__((ext_vector_type(8))) short;
using short4v = __attribute__((ext_vector_type(4))) short;
using f32x4  = __attribute__((ext_vector_type(4))) float;

__device__ inline unsigned pk2(float lo, float hi) {
    __hip_bfloat162 h = __float22bfloat162_rn(float2{lo, hi});
    return *reinterpret_cast<unsigned*>(&h);
}
__device__ inline short8 cvt8(float4 a, float4 b) {
    union { unsigned u[4]; short8 s; } r;
    r.u[0] = pk2(a.x, a.y); r.u[1] = pk2(a.z, a.w);
    r.u[2] = pk2(b.x, b.y); r.u[3] = pk2(b.z, b.w);
    return r.s;
}
__device__ inline float ftanh(float x) {
    float e = __expf(2.f * x);
    return 1.f - 2.f / (e + 1.f);
}
__device__ inline void gload16(const void* g, void* lds) {
    __builtin_amdgcn_global_load_lds(
        (const __attribute__((address_space(1))) unsigned int*)g,
        (__attribute__((address_space(3))) unsigned int*)lds, 16, 0, 0);
}
__device__ inline short f2b(float f) {
    unsigned u = __float_as_uint(f);
    return (short)((u + 0x7FFFu + ((u >> 16) & 1u)) >> 16);
}

// streaming K=1024 pass over xcat_bf (row stride 3072): 4 MFMAs / 32-K step
__device__ inline void xcat_pass(const short* __restrict__ ap,
                                 const float* __restrict__ bp, f32x4 (&acc)[4]) {
#pragma unroll 4
    for (int k0 = 0; k0 < 1024; k0 += 32) {
        float4 b0 = *(const float4*)(bp + k0);
        float4 b1 = *(const float4*)(bp + k0 + 4);
        short8 bf = cvt8(b0, b1);
        short8 a0 = *(const short8*)(ap + k0);
        short8 a1 = *(const short8*)(ap + k0 + 16 * 3072);
        short8 a2 = *(const short8*)(ap + k0 + 32 * 3072);
        short8 a3 = *(const short8*)(ap + k0 + 48 * 3072);
        acc[0] = __builtin_amdgcn_mfma_f32_16x16x32_bf16(a0, bf, acc[0], 0, 0, 0);
        acc[1] = __builtin_amdgcn_mfma_f32_16x16x32_bf16(a1, bf, acc[1], 0, 0, 0);
        acc[2] = __builtin_amdgcn_mfma_f32_16x16x32_bf16(a2, bf, acc[2], 0, 0, 0);
        acc[3] = __builtin_amdgcn_mfma_f32_16x16x32_bf16(a3, bf, acc[3], 0, 0, 0);
    }
}

// ---------------------------------------------------------------------------
// K1: fused [enc+Ua cvt/swizzle | qp streaming GEMM | xcat gather + zero].
// grid 2348 x 512.
__global__ __launch_bounds__(512) void k_fused1(
    const float* __restrict__ enc, const float* __restrict__ Ua,
    short* __restrict__ encua_bf,
    const float* __restrict__ hidden, const float* __restrict__ Wa,
    float* __restrict__ qp,
    const int* __restrict__ idx, const float* __restrict__ emb,
    short* __restrict__ xcat_bf, float4* __restrict__ scores4) {
    const int bid = blockIdx.x, t = threadIdx.x;
    if (bid < 2304) {
        // cvt role: dst[row][seg][g] = cvt(src[row][seg][g ^ (row&7)])
        int i = bid * 512 + t;  // < 9216*128
        int row = i >> 7, gi = i & 127;
        int seg = gi >> 3, g = gi & 7;
        const float* src = (row < 8192) ? enc + ((size_t)row << 10)
                                        : Ua + ((size_t)(row - 8192) << 10);
        const float* p = src + (seg << 6) + ((g ^ (row & 7)) << 3);
        *(short8*)&encua_bf[(size_t)i << 3] =
            cvt8(*(const float4*)p, *(const float4*)(p + 4));
    } else if (bid < 2312) {
        // qp role: barrier-free streaming, wave = 16 cols, K=1024 full.
        const int l = t & 63, wv = t >> 6;
        const int lr = l & 15, lg = l >> 4;
        const int n0 = (bid - 2304) * 128 + wv * 16;
        f32x4 acc[4];
#pragma unroll
        for (int i = 0; i < 4; ++i) { f32x4 z = {0.f, 0.f, 0.f, 0.f}; acc[i] = z; }
        const float* ap = hidden + lr * 1024 + lg * 8;
        const float* bp = Wa + (size_t)(n0 + lr) * 1024 + lg * 8;
#pragma unroll 4
        for (int k0 = 0; k0 < 1024; k0 += 32) {
            short8 bf = cvt8(*(const float4*)(bp + k0), *(const float4*)(bp + k0 + 4));
            short8 a0 = cvt8(*(const float4*)(ap + k0), *(const float4*)(ap + k0 + 4));
            short8 a1 = cvt8(*(const float4*)(ap + k0 + 16384), *(const float4*)(ap + k0 + 16388));
            short8 a2 = cvt8(*(const float4*)(ap + k0 + 32768), *(const float4*)(ap + k0 + 32772));
            short8 a3 = cvt8(*(const float4*)(ap + k0 + 49152), *(const float4*)(ap + k0 + 49156));
            acc[0] = __builtin_amdgcn_mfma_f32_16x16x32_bf16(a0, bf, acc[0], 0, 0, 0);
            acc[1] = __builtin_amdgcn_mfma_f32_16x16x32_bf16(a1, bf, acc[1], 0, 0, 0);
            acc[2] = __builtin_amdgcn_mfma_f32_16x16x32_bf16(a2, bf, acc[2], 0, 0, 0);
            acc[3] = __builtin_amdgcn_mfma_f32_16x16x32_bf16(a3, bf, acc[3], 0, 0, 0);
        }
#pragma unroll
        for (int i = 0; i < 4; ++i)
#pragma unroll
            for (int r = 0; r < 4; ++r)
                qp[(size_t)(i * 16 + lg * 4 + r) * 1024 + n0 + lr] = acc[i][r];
    } else {
        // aux role: xcat_bf gather (emb|..|h0) + zero scores
        int j = (bid - 2312) * 512 + t;  // < 18432
        if (j < 16384) {
            int b = j >> 8, g = j & 255;
            if (g < 128) {
                const float* p = emb + (size_t)idx[b] * 1024 + g * 8;
                *(short8*)&xcat_bf[b * 3072 + g * 8] =
                    cvt8(*(const float4*)p, *(const float4*)(p + 4));
            } else {
                const float* p = hidden + (size_t)b * 1024 + (g - 128) * 8;
                *(short8*)&xcat_bf[b * 3072 + 2048 + (g - 128) * 8] =
                    cvt8(*(const float4*)p, *(const float4*)(p + 4));
            }
        } else {
            float4 z = {0.f, 0.f, 0.f, 0.f};
            scores4[j - 16384] = z;
        }
    }
}

// ---------------------------------------------------------------------------
// K2: fused [attention-score GEMM (blocks 0..255) | gates part-1 (256..287)].
// attn: 256x128 tile, BK=64, global_load_lds, 8 waves, tanh/Va epilogue.
// gates1: per wave 16 cols; emb x W_ih[:,:1024] + h0 x W_hh -> gates_p0.
__global__ __launch_bounds__(512) void k_attn_gates(
    const short* __restrict__ encua_bf,
    const float* __restrict__ Uab, const float* __restrict__ Wab,
    const float* __restrict__ qp, const float* __restrict__ Va,
    float* __restrict__ scores,
    const short* __restrict__ xcat_bf, const float* __restrict__ Wih,
    const float* __restrict__ Whh, float* __restrict__ gp0) {
    __shared__ short As[256 * 64];
    __shared__ short Bs[128 * 64];
    const int bid = blockIdx.x, t = threadIdx.x;
    const int l = t & 63, w = t >> 6;
    const int lr = l & 15, lg = l >> 4;

    if (bid < 256) {
        const int wm = w >> 1, wn = w & 1;
        const int n0 = (bid & 7) * 128;
        const int r0 = (bid >> 3) * 256;

        f32x4 acc[4][4];
#pragma unroll
        for (int i = 0; i < 4; ++i)
#pragma unroll
            for (int j = 0; j < 4; ++j) { f32x4 z = {0.f, 0.f, 0.f, 0.f}; acc[i][j] = z; }

        for (int seg = 0; seg < 16; ++seg) {
#pragma unroll
            for (int i = 0; i < 4; ++i) {
                int base = i * 512 + w * 64;  // wave-uniform slot base
                int s = base + l;
                gload16(encua_bf + (((size_t)r0 + (s >> 3)) << 10) + (seg << 6) + ((s & 7) << 3),
                        (void*)&As[base * 8]);
                if (i < 2)
                    gload16(encua_bf + (((size_t)8192 + n0 + (s >> 3)) << 10) + (seg << 6) + ((s & 7) << 3),
                            (void*)&Bs[base * 8]);
            }
            __syncthreads();
#pragma unroll
            for (int kh = 0; kh < 2; ++kh) {
                short8 a[4], b[4];
#pragma unroll
                for (int i = 0; i < 4; ++i) {
                    int ra = wm * 64 + i * 16 + lr;
                    a[i] = *(const short8*)&As[ra * 64 + (((kh * 4 + lg) ^ (ra & 7)) << 3)];
                    int rb = wn * 64 + i * 16 + lr;
                    b[i] = *(const short8*)&Bs[rb * 64 + (((kh * 4 + lg) ^ (rb & 7)) << 3)];
                }
#pragma unroll
                for (int i = 0; i < 4; ++i)
#pragma unroll
                    for (int j = 0; j < 4; ++j)
                        acc[i][j] = __builtin_amdgcn_mfma_f32_16x16x32_bf16(a[i], b[j], acc[i][j], 0, 0, 0);
            }
            __syncthreads();
        }

        float va[4], ub[4];
#pragma unroll
        for (int j = 0; j < 4; ++j) {
            int h = n0 + wn * 64 + j * 16 + lr;
            va[j] = Va[h];
            ub[j] = Uab[h] + Wab[h];
        }
#pragma unroll
        for (int i = 0; i < 4; ++i)
#pragma unroll
            for (int r = 0; r < 4; ++r) {
                int row = r0 + wm * 64 + i * 16 + lg * 4 + r;
                const float* qpb = qp + (size_t)(row >> 7) * 1024;
                float s = 0.f;
#pragma unroll
                for (int j = 0; j < 4; ++j) {
                    int h = n0 + wn * 64 + j * 16 + lr;
                    s += va[j] * ftanh(acc[i][j][r] + qpb[h] + ub[j]);
                }
                s += __shfl_xor(s, 1);
                s += __shfl_xor(s, 2);
                s += __shfl_xor(s, 4);
                s += __shfl_xor(s, 8);
                if (lr == 0) atomicAdd(scores + row, s);
            }
    } else {
        // gates part-1: 32 blocks x 8 waves x 16 cols = 4096
        const int n0 = (bid - 256) * 128 + w * 16;
        f32x4 acc[4];
#pragma unroll
        for (int i = 0; i < 4; ++i) { f32x4 z = {0.f, 0.f, 0.f, 0.f}; acc[i] = z; }
        xcat_pass(xcat_bf + lr * 3072 + lg * 8,
                  Wih + (size_t)(n0 + lr) * 2048 + lg * 8, acc);
        xcat_pass(xcat_bf + lr * 3072 + 2048 + lg * 8,
                  Whh + (size_t)(n0 + lr) * 1024 + lg * 8, acc);
#pragma unroll
        for (int i = 0; i < 4; ++i)
#pragma unroll
            for (int r = 0; r < 4; ++r)
                gp0[(size_t)(i * 16 + lg * 4 + r) * 4096 + n0 + lr] = acc[i][r];
    }
}

// ---------------------------------------------------------------------------
// K3: fused softmax + context (one block per batch); ctx via float4 loads.
__global__ __launch_bounds__(256) void k_smctx(
    const float* __restrict__ scores, const float* __restrict__ enc,
    float* __restrict__ wout, short* __restrict__ xcat_bf) {
    int b = blockIdx.x;
    int t = threadIdx.x;
    __shared__ float buf[128];
    __shared__ float wsb[128];
    if (t < 128) buf[t] = scores[b * 128 + t];
    __syncthreads();
    if (t < 64) buf[t] = fmaxf(buf[t], buf[t + 64]);
    __syncthreads();
    if (t < 32) buf[t] = fmaxf(buf[t], buf[t + 32]);
    __syncthreads();
    float m;
    {
        float v = buf[t & 31];
        for (int off = 16; off > 0; off >>= 1)
            v = fmaxf(v, __shfl_xor(v, off, 32));
        m = v;
    }
    __syncthreads();
    if (t < 128) wsb[t] = __expf(scores[b * 128 + t] - m);
    __syncthreads();
    if (t < 64) buf[t] = wsb[t] + wsb[t + 64];
    __syncthreads();
    if (t < 32) buf[t] += buf[t + 32];
    __syncthreads();
    float sum;
    {
        float v = buf[t & 31];
        for (int off = 16; off > 0; off >>= 1)
            v += __shfl_xor(v, off, 32);
        sum = v;
    }
    float inv = 1.f / sum;
    __syncthreads();
    if (t < 128) {
        wsb[t] *= inv;
        wout[b * 128 + t] = wsb[t];
    }
    __syncthreads();
    // context: thread t -> h in [4t, 4t+4), float4 loads of enc
    float4 acc = {0.f, 0.f, 0.f, 0.f};
    const float* base = enc + (size_t)b * 131072 + t * 4;
    for (int s = 0; s < 128; ++s) {
        float wv = wsb[s];
        float4 v = *(const float4*)(base + s * 1024);
        acc.x += wv * v.x; acc.y += wv * v.y;
        acc.z += wv * v.z; acc.w += wv * v.w;
    }
    short4v o;
    o[0] = f2b(acc.x); o[1] = f2b(acc.y); o[2] = f2b(acc.z); o[3] = f2b(acc.w);
    *(short4v*)&xcat_bf[(size_t)b * 3072 + 1024 + t * 4] = o;
}

// ---------------------------------------------------------------------------
// K4: gates part-2 (ctx x W_ih[:,1024:2048]) -> gates_p1. grid 32 x 512.
__global__ __launch_bounds__(512) void k_gates2(
    const short* __restrict__ xcat_bf, const float* __restrict__ Wih,
    float* __restrict__ gp1) {
    const int t = threadIdx.x;
    const int l = t & 63, w = t >> 6;
    const int lr = l & 15, lg = l >> 4;
    const int n0 = blockIdx.x * 128 + w * 16;
    f32x4 acc[4];
#pragma unroll
    for (int i = 0; i < 4; ++i) { f32x4 z = {0.f, 0.f, 0.f, 0.f}; acc[i] = z; }
    xcat_pass(xcat_bf + lr * 3072 + 1024 + lg * 8,
              Wih + (size_t)(n0 + lr) * 2048 + 1024 + lg * 8, acc);
#pragma unroll
    for (int i = 0; i < 4; ++i)
#pragma unroll
        for (int r = 0; r < 4; ++r)
            gp1[(size_t)(i * 16 + lg * 4 + r) * 4096 + n0 + lr] = acc[i][r];
}

// ---------------------------------------------------------------------------
// K5: LSTM pointwise; sums 2 gate partials + biases; emits h1 f32 and bf16.
__global__ void k_lstm2(const float* __restrict__ gp, const float* __restrict__ c0,
                        const float* __restrict__ b_ih, const float* __restrict__ b_hh,
                        float* __restrict__ h1, float* __restrict__ c1,
                        short* __restrict__ h1bf) {
    int idx = blockIdx.x * blockDim.x + threadIdx.x;  // 65536
    int b = idx >> 10, h = idx & 1023;
    const float* g0 = gp + (size_t)b * 4096;
    float iv = b_ih[h] + b_hh[h];
    float fv = b_ih[1024 + h] + b_hh[1024 + h];
    float gv = b_ih[2048 + h] + b_hh[2048 + h];
    float ov = b_ih[3072 + h] + b_hh[3072 + h];
#pragma unroll
    for (int p = 0; p < 2; ++p) {
        const float* g = g0 + p * 262144;
        iv += g[h];
        fv += g[1024 + h];
        gv += g[2048 + h];
        ov += g[3072 + h];
    }
    float si = 1.f / (1.f + expf(-iv));
    float sf = 1.f / (1.f + expf(-fv));
    float so = 1.f / (1.f + expf(-ov));
    float tg = tanhf(gv);
    float cc = sf * c0[idx] + si * tg;
    float hh = so * tanhf(cc);
    c1[idx] = cc;
    h1[idx] = hh;
    h1bf[idx] = f2b(hh);
}

// ---------------------------------------------------------------------------
// K6: barrier-free streaming logits GEMM (R10 k_vgemm). grid 500 x 256.
__global__ __launch_bounds__(256) void k_vgemm(
    const short* __restrict__ Abf, const float* __restrict__ B,
    const float* __restrict__ bias, float* __restrict__ C) {
    const int t = threadIdx.x;
    const int l = t & 63, w = t >> 6;
    const int lr = l & 15, lg = l >> 4;
    const int n0 = blockIdx.x * 64 + w * 16;

    f32x4 acc[4];
#pragma unroll
    for (int i = 0; i < 4; ++i) { f32x4 z = {0.f, 0.f, 0.f, 0.f}; acc[i] = z; }

    const float* bp = B + (size_t)(n0 + lr) * 1024 + lg * 8;
    const short* ap = Abf + lr * 1024 + lg * 8;

#pragma unroll 4
    for (int k0 = 0; k0 < 1024; k0 += 32) {
        float4 b0 = *(const float4*)(bp + k0);
        float4 b1 = *(const float4*)(bp + k0 + 4);
        short8 a0 = *(const short8*)(ap + k0);
        short8 a1 = *(const short8*)(ap + k0 + 16 * 1024);
        short8 a2 = *(const short8*)(ap + k0 + 32 * 1024);
        short8 a3 = *(const short8*)(ap + k0 + 48 * 1024);
        short8 bf = cvt8(b0, b1);
        acc[0] = __builtin_amdgcn_mfma_f32_16x16x32_bf16(a0, bf, acc[0], 0, 0, 0);
        acc[1] = __builtin_amdgcn_mfma_f32_16x16x32_bf16(a1, bf, acc[1], 0, 0, 0);
        acc[2] = __builtin_amdgcn_mfma_f32_16x16x32_bf16(a2, bf, acc[2], 0, 0, 0);
        acc[3] = __builtin_amdgcn_mfma_f32_16x16x32_bf16(a3, bf, acc[3], 0, 0, 0);
    }

    float bv = bias[n0 + lr];
#pragma unroll
    for (int i = 0; i < 4; ++i)
#pragma unroll
        for (int r = 0; r < 4; ++r)
            C[(size_t)(i * 16 + lg * 4 + r) * 32000 + n0 + lr] = acc[i][r] + bv;
}

// ---------------------------------------------------------------------------
extern "C" void kernel_launch(void* const* d_in, const int* in_sizes, int n_in,
                              void* d_out, int out_size, void* d_ws, size_t ws_size,
                              hipStream_t stream) {
    const int* idx = (const int*)d_in[0];
    const float* hidden = (const float*)d_in[1];
    const float* cell = (const float*)d_in[2];
    const float* enc = (const float*)d_in[3];
    const float* emb = (const float*)d_in[4];
    const float* Wa_w = (const float*)d_in[5];
    const float* Wa_b = (const float*)d_in[6];
    const float* Ua_w = (const float*)d_in[7];
    const float* Ua_b = (const float*)d_in[8];
    const float* Va_w = (const float*)d_in[9];
    // d_in[10] Va_b unused: softmax shift-invariant
    const float* W_ih = (const float*)d_in[11];
    const float* W_hh = (const float*)d_in[12];
    const float* b_ih = (const float*)d_in[13];
    const float* b_hh = (const float*)d_in[14];
    const float* out_w = (const float*)d_in[15];
    const float* out_b = (const float*)d_in[16];

    float* out = (float*)d_out;
    float* logits = out;                             // 64*32000
    float* h1 = out + 2048000;                       // 64*1024
    float* c1 = out + 2048000 + 65536;               // 64*1024
    float* wts = out + 2048000 + 65536 + 65536;      // 64*128

    // ws layout (float offsets):
    float* ws = (float*)d_ws;
    float* qp = ws;                            // 65536
    float* scores = ws + 65536;                // 8192
    short* xcat_bf = (short*)(ws + 73728);     // 196608 shorts = 98304 f
    float* gates_p = ws + 172032;              // 2*262144 = 524288
    short* h1_bf = (short*)(ws + 696320);      // 65536 shorts = 32768 f
    short* encua_bf = (short*)(ws + 729088);   // 9216*1024 shorts

    // K1: cvt (2304 blocks) | qp (8) | gather+zero (36)
    k_fused1<<<2348, 512, 0, stream>>>(enc, Ua_w, encua_bf, hidden, Wa_w, qp,
                                       idx, emb, xcat_bf, (float4*)scores);
    // K2: attn scores (256) | gates part-1 (32)
    k_attn_gates<<<288, 512, 0, stream>>>(encua_bf, Ua_b, Wa_b, qp, Va_w, scores,
                                          xcat_bf, W_ih, W_hh, gates_p);
    // K3: softmax + context
    k_smctx<<<64, 256, 0, stream>>>(scores, enc, wts, xcat_bf);
    // K4: gates part-2 (ctx slice)
    k_gates2<<<32, 512, 0, stream>>>(xcat_bf, W_ih, gates_p + 262144);
    // K5: LSTM (sums 2 partials + biases), writes h1 f32 + bf16
    k_lstm2<<<256, 256, 0, stream>>>(gates_p, cell, b_ih, b_hh, h1, c1, h1_bf);
    // K6: logits streaming GEMM
    k_vgemm<<<500, 256, 0, stream>>>(h1_bf, out_w, out_b, logits);
}

// Round 13
// 139.051 us; speedup vs baseline: 2.1526x; 2.1526x over previous
//
#include <hip/hip_runtime.h>
#include <hip/hip_bf16.h>

using short8 = __attribute__((ext_vector_type(8))) short;
using f32x4  = __attribute__((ext_vector_type(4))) float;

__device__ inline unsigned pk2(float lo, float hi) {
    __hip_bfloat162 h = __float22bfloat162_rn(float2{lo, hi});
    return *reinterpret_cast<unsigned*>(&h);
}
__device__ inline short8 cvt8(float4 a, float4 b) {
    union { unsigned u[4]; short8 s; } r;
    r.u[0] = pk2(a.x, a.y); r.u[1] = pk2(a.z, a.w);
    r.u[2] = pk2(b.x, b.y); r.u[3] = pk2(b.z, b.w);
    return r.s;
}
__device__ inline float ftanh(float x) {
    float e = __expf(2.f * x);
    return 1.f - 2.f / (e + 1.f);
}
__device__ inline void gload16(const void* g, void* lds) {
    __builtin_amdgcn_global_load_lds(
        (const __attribute__((address_space(1))) unsigned int*)g,
        (__attribute__((address_space(3))) unsigned int*)lds, 16, 0, 0);
}
__device__ inline short f2b(float f) {
    unsigned u = __float_as_uint(f);
    return (short)((u + 0x7FFFu + ((u >> 16) & 1u)) >> 16);
}

// ---------------------------------------------------------------------------
// Fused init: [0,18432) float4-zero of qp|scores; [18432,67584) xcat gather.
__global__ void k_init(const int* __restrict__ idx, const float* __restrict__ emb,
                       const float* __restrict__ h0, float* __restrict__ xcat,
                       float4* __restrict__ wsz) {
    int i = blockIdx.x * blockDim.x + threadIdx.x;
    if (i < 18432) {
        float4 z = {0.f, 0.f, 0.f, 0.f};
        wsz[i] = z;
    } else if (i < 67584) {
        int j = i - 18432;
        int b = j / 768, q = j - b * 768;
        if (q < 256)
            ((float4*)(xcat + (size_t)b * 3072))[q] =
                ((const float4*)(emb + (size_t)idx[b] * 1024))[q];
        else if (q >= 512)
            ((float4*)(xcat + (size_t)b * 3072))[q] =
                ((const float4*)(h0 + (size_t)b * 1024))[q - 512];
    }
}

// ---------------------------------------------------------------------------
// f32 -> bf16 with granule pre-swizzle; rows 0..8191 enc, 8192+ Ua.
__global__ void k_cvt_swz(const float* __restrict__ enc, const float* __restrict__ Ua,
                          short* __restrict__ dst) {
    int i = blockIdx.x * blockDim.x + threadIdx.x;  // 9216*128 granules
    if (i >= 9216 * 128) return;
    int row = i >> 7, gi = i & 127;
    int seg = gi >> 3, g = gi & 7;
    const float* src = (row < 8192) ? enc + ((size_t)row << 10)
                                    : Ua + ((size_t)(row - 8192) << 10);
    const float* p = src + (seg << 6) + ((g ^ (row & 7)) << 3);
    float4 v0 = *(const float4*)p;
    float4 v1 = *(const float4*)(p + 4);
    *(short8*)&dst[(size_t)i << 3] = cvt8(v0, v1);
}

// ---------------------------------------------------------------------------
// Attention-score GEMM, 256x128 tile, BK=64, global_load_lds staging with
// 2-PHASE DOUBLE BUFFER: issue seg+1 loads BEFORE computing seg; single
// barrier per seg (compiler's pre-barrier vmcnt(0) drain lands after compute,
// so HBM latency hides under the 32-MFMA phase). 512 thr = 8 waves (4M x 2N).
__global__ __launch_bounds__(512) void k_attn2(
    const short* __restrict__ Abf, const short* __restrict__ Bbf,
    const float* __restrict__ Uab, const float* __restrict__ Wab,
    const float* __restrict__ qp, const float* __restrict__ Va,
    float* __restrict__ scores) {
    __shared__ short As[2][256 * 64];   // 64 KB
    __shared__ short Bs[2][128 * 64];   // 32 KB
    const int t = threadIdx.x;
    const int l = t & 63, w = t >> 6;
    const int wm = w >> 1, wn = w & 1;
    const int lr = l & 15, lg = l >> 4;
    const int n0 = blockIdx.x * 128;
    const int r0 = blockIdx.y * 256;

    f32x4 acc[4][4];
#pragma unroll
    for (int i = 0; i < 4; ++i)
#pragma unroll
        for (int j = 0; j < 4; ++j) { f32x4 z = {0.f, 0.f, 0.f, 0.f}; acc[i][j] = z; }

    auto STAGE = [&](int buf, int seg) {
#pragma unroll
        for (int i = 0; i < 4; ++i) {
            int base = i * 512 + w * 64;  // wave-uniform slot base
            int s = base + l;
            gload16(Abf + (((size_t)r0 + (s >> 3)) << 10) + (seg << 6) + ((s & 7) << 3),
                    (void*)&As[buf][base * 8]);
            if (i < 2)
                gload16(Bbf + (((size_t)8192 + n0 + (s >> 3)) << 10) + (seg << 6) + ((s & 7) << 3),
                        (void*)&Bs[buf][base * 8]);
        }
    };

    STAGE(0, 0);
    __syncthreads();  // drains vmcnt(0): buf0 ready

    for (int seg = 0; seg < 16; ++seg) {
        const int cur = seg & 1;
        if (seg < 15) STAGE(cur ^ 1, seg + 1);  // async loads fly during compute
#pragma unroll
        for (int kh = 0; kh < 2; ++kh) {
            short8 a[4], b[4];
#pragma unroll
            for (int i = 0; i < 4; ++i) {
                int ra = wm * 64 + i * 16 + lr;
                a[i] = *(const short8*)&As[cur][ra * 64 + (((kh * 4 + lg) ^ (ra & 7)) << 3)];
                int rb = wn * 64 + i * 16 + lr;
                b[i] = *(const short8*)&Bs[cur][rb * 64 + (((kh * 4 + lg) ^ (rb & 7)) << 3)];
            }
#pragma unroll
            for (int i = 0; i < 4; ++i)
#pragma unroll
                for (int j = 0; j < 4; ++j)
                    acc[i][j] = __builtin_amdgcn_mfma_f32_16x16x32_bf16(a[i], b[j], acc[i][j], 0, 0, 0);
        }
        __syncthreads();  // drain: next buf loaded; all waves done reading cur
    }

    float va[4], ub[4];
#pragma unroll
    for (int j = 0; j < 4; ++j) {
        int h = n0 + wn * 64 + j * 16 + lr;
        va[j] = Va[h];
        ub[j] = Uab[h] + Wab[h];
    }
#pragma unroll
    for (int i = 0; i < 4; ++i)
#pragma unroll
        for (int r = 0; r < 4; ++r) {
            int row = r0 + wm * 64 + i * 16 + lg * 4 + r;
            const float* qpb = qp + (size_t)(row >> 7) * 1024;
            float s = 0.f;
#pragma unroll
            for (int j = 0; j < 4; ++j) {
                int h = n0 + wn * 64 + j * 16 + lr;
                s += va[j] * ftanh(acc[i][j][r] + qpb[h] + ub[j]);
            }
            s += __shfl_xor(s, 1);
            s += __shfl_xor(s, 2);
            s += __shfl_xor(s, 4);
            s += __shfl_xor(s, 8);
            if (lr == 0) atomicAdd(scores + row, s);
        }
}

// ---------------------------------------------------------------------------
// Skinny split-K GEMM. EPI 1: atomicAdd into C (C pre-zeroed).
// EPI 0: store into partial buffer C + ky*pstride.
template <int EPI>
__global__ __launch_bounds__(256) void k_sgemm(
    const float* __restrict__ A, int lda,
    const float* __restrict__ B0, int ldb0,
    const float* __restrict__ B1, int ldb1, int kyB1,
    float* __restrict__ C, int ldc, int Kblk, int pstride) {
    __shared__ short As[64 * 64];
    __shared__ short Bs[64 * 64];
    const int t = threadIdx.x;
    const int l = t & 63, w = t >> 6;
    const int wm = w >> 1, wn = w & 1;
    const int lr = l & 15, lg = l >> 4;
    const int n0 = blockIdx.x * 64;
    const int ky = blockIdx.y;

    const float* Ab = A + (size_t)ky * Kblk;
    const float* Bb;
    int ldb;
    if (ky < kyB1) { Bb = B0 + (size_t)ky * Kblk; ldb = ldb0; }
    else           { Bb = B1 + (size_t)(ky - kyB1) * Kblk; ldb = ldb1; }

    f32x4 acc[2][2];
#pragma unroll
    for (int i = 0; i < 2; ++i)
#pragma unroll
        for (int j = 0; j < 2; ++j) { f32x4 z = {0.f, 0.f, 0.f, 0.f}; acc[i][j] = z; }

    for (int kt = 0; kt < Kblk; kt += 64) {
#pragma unroll
        for (int i = 0; i < 2; ++i) {
            int s = t + 256 * i, row = s >> 3, ch = s & 7;
            const float* p = Ab + (size_t)row * lda + kt + ch * 8;
            *(short8*)&As[row * 64 + ((ch ^ (row & 7)) << 3)] =
                cvt8(*(const float4*)p, *(const float4*)(p + 4));
            const float* q = Bb + (size_t)(n0 + row) * ldb + kt + ch * 8;
            *(short8*)&Bs[row * 64 + ((ch ^ (row & 7)) << 3)] =
                cvt8(*(const float4*)q, *(const float4*)(q + 4));
        }
        __syncthreads();
#pragma unroll
        for (int kh = 0; kh < 2; ++kh) {
            short8 a[2], b[2];
#pragma unroll
            for (int i = 0; i < 2; ++i) {
                int ra = wm * 32 + i * 16 + lr;
                a[i] = *(const short8*)&As[ra * 64 + (((kh * 4 + lg) ^ (ra & 7)) << 3)];
                int rb = wn * 32 + i * 16 + lr;
                b[i] = *(const short8*)&Bs[rb * 64 + (((kh * 4 + lg) ^ (rb & 7)) << 3)];
            }
#pragma unroll
            for (int i = 0; i < 2; ++i)
#pragma unroll
                for (int j = 0; j < 2; ++j)
                    acc[i][j] = __builtin_amdgcn_mfma_f32_16x16x32_bf16(a[i], b[j], acc[i][j], 0, 0, 0);
        }
        __syncthreads();
    }

    float* Cp = (EPI == 0) ? C + (size_t)ky * pstride : C;
#pragma unroll
    for (int i = 0; i < 2; ++i)
#pragma unroll
        for (int j = 0; j < 2; ++j)
#pragma unroll
            for (int r = 0; r < 4; ++r) {
                int R = wm * 32 + i * 16 + lg * 4 + r;
                int c = n0 + wn * 32 + j * 16 + lr;
                if constexpr (EPI == 1)
                    atomicAdd(&C[(size_t)R * ldc + c], acc[i][j][r]);
                else
                    Cp[(size_t)R * ldc + c] = acc[i][j][r];
            }
}

// ---------------------------------------------------------------------------
// Barrier-free streaming GEMM for logits: C(64 x 32000) = h1 @ out_w^T + b.
__global__ __launch_bounds__(256) void k_vgemm(
    const short* __restrict__ Abf, const float* __restrict__ B,
    const float* __restrict__ bias, float* __restrict__ C) {
    const int t = threadIdx.x;
    const int l = t & 63, w = t >> 6;
    const int lr = l & 15, lg = l >> 4;
    const int n0 = blockIdx.x * 64 + w * 16;

    f32x4 acc[4];
#pragma unroll
    for (int i = 0; i < 4; ++i) { f32x4 z = {0.f, 0.f, 0.f, 0.f}; acc[i] = z; }

    const float* bp = B + (size_t)(n0 + lr) * 1024 + lg * 8;
    const short* ap = Abf + lr * 1024 + lg * 8;

#pragma unroll 4
    for (int k0 = 0; k0 < 1024; k0 += 32) {
        float4 b0 = *(const float4*)(bp + k0);
        float4 b1 = *(const float4*)(bp + k0 + 4);
        short8 a0 = *(const short8*)(ap + k0);
        short8 a1 = *(const short8*)(ap + k0 + 16 * 1024);
        short8 a2 = *(const short8*)(ap + k0 + 32 * 1024);
        short8 a3 = *(const short8*)(ap + k0 + 48 * 1024);
        short8 bf = cvt8(b0, b1);
        acc[0] = __builtin_amdgcn_mfma_f32_16x16x32_bf16(a0, bf, acc[0], 0, 0, 0);
        acc[1] = __builtin_amdgcn_mfma_f32_16x16x32_bf16(a1, bf, acc[1], 0, 0, 0);
        acc[2] = __builtin_amdgcn_mfma_f32_16x16x32_bf16(a2, bf, acc[2], 0, 0, 0);
        acc[3] = __builtin_amdgcn_mfma_f32_16x16x32_bf16(a3, bf, acc[3], 0, 0, 0);
    }

    float bv = bias[n0 + lr];
#pragma unroll
    for (int i = 0; i < 4; ++i)
#pragma unroll
        for (int r = 0; r < 4; ++r)
            C[(size_t)(i * 16 + lg * 4 + r) * 32000 + n0 + lr] = acc[i][r] + bv;
}

// ---------------------------------------------------------------------------
// Fused softmax + context (one block per batch).
__global__ __launch_bounds__(256) void k_smctx(
    const float* __restrict__ scores, const float* __restrict__ enc,
    float* __restrict__ wout, float* __restrict__ xcat) {
    int b = blockIdx.x;
    int t = threadIdx.x;
    __shared__ float buf[128];
    __shared__ float wsb[128];
    if (t < 128) buf[t] = scores[b * 128 + t];
    __syncthreads();
    if (t < 64) buf[t] = fmaxf(buf[t], buf[t + 64]);
    __syncthreads();
    if (t < 32) buf[t] = fmaxf(buf[t], buf[t + 32]);
    __syncthreads();
    float m;
    {
        float v = buf[t & 31];
        for (int off = 16; off > 0; off >>= 1)
            v = fmaxf(v, __shfl_xor(v, off, 32));
        m = v;
    }
    __syncthreads();
    if (t < 128) wsb[t] = __expf(scores[b * 128 + t] - m);
    __syncthreads();
    if (t < 64) buf[t] = wsb[t] + wsb[t + 64];
    __syncthreads();
    if (t < 32) buf[t] += buf[t + 32];
    __syncthreads();
    float sum;
    {
        float v = buf[t & 31];
        for (int off = 16; off > 0; off >>= 1)
            v += __shfl_xor(v, off, 32);
        sum = v;
    }
    float inv = 1.f / sum;
    __syncthreads();
    if (t < 128) {
        wsb[t] *= inv;
        wout[b * 128 + t] = wsb[t];
    }
    __syncthreads();
    float acc[4] = {0.f, 0.f, 0.f, 0.f};
    for (int s = 0; s < 128; ++s) {
        float wv = wsb[s];
        const float* row = enc + ((size_t)b * 128 + s) * 1024;
#pragma unroll
        for (int j = 0; j < 4; ++j) acc[j] += wv * row[t + 256 * j];
    }
#pragma unroll
    for (int j = 0; j < 4; ++j) xcat[(size_t)b * 3072 + 1024 + t + 256 * j] = acc[j];
}

// ---------------------------------------------------------------------------
// LSTM pointwise; sums 6 gate partials + biases; also emits h1 as bf16.
__global__ void k_lstm6(const float* __restrict__ gp, const float* __restrict__ c0,
                        const float* __restrict__ b_ih, const float* __restrict__ b_hh,
                        float* __restrict__ h1, float* __restrict__ c1,
                        short* __restrict__ h1bf) {
    int idx = blockIdx.x * blockDim.x + threadIdx.x;  // 65536
    int b = idx >> 10, h = idx & 1023;
    const float* g0 = gp + (size_t)b * 4096;
    float iv = b_ih[h] + b_hh[h];
    float fv = b_ih[1024 + h] + b_hh[1024 + h];
    float gv = b_ih[2048 + h] + b_hh[2048 + h];
    float ov = b_ih[3072 + h] + b_hh[3072 + h];
#pragma unroll
    for (int p = 0; p < 6; ++p) {
        const float* g = g0 + p * 262144;
        iv += g[h];
        fv += g[1024 + h];
        gv += g[2048 + h];
        ov += g[3072 + h];
    }
    float si = 1.f / (1.f + expf(-iv));
    float sf = 1.f / (1.f + expf(-fv));
    float so = 1.f / (1.f + expf(-ov));
    float tg = tanhf(gv);
    float cc = sf * c0[idx] + si * tg;
    float hh = so * tanhf(cc);
    c1[idx] = cc;
    h1[idx] = hh;
    h1bf[idx] = f2b(hh);
}

// ---------------------------------------------------------------------------
extern "C" void kernel_launch(void* const* d_in, const int* in_sizes, int n_in,
                              void* d_out, int out_size, void* d_ws, size_t ws_size,
                              hipStream_t stream) {
    const int* idx = (const int*)d_in[0];
    const float* hidden = (const float*)d_in[1];
    const float* cell = (const float*)d_in[2];
    const float* enc = (const float*)d_in[3];
    const float* emb = (const float*)d_in[4];
    const float* Wa_w = (const float*)d_in[5];
    const float* Wa_b = (const float*)d_in[6];
    const float* Ua_w = (const float*)d_in[7];
    const float* Ua_b = (const float*)d_in[8];
    const float* Va_w = (const float*)d_in[9];
    // d_in[10] Va_b unused: softmax shift-invariant
    const float* W_ih = (const float*)d_in[11];
    const float* W_hh = (const float*)d_in[12];
    const float* b_ih = (const float*)d_in[13];
    const float* b_hh = (const float*)d_in[14];
    const float* out_w = (const float*)d_in[15];
    const float* out_b = (const float*)d_in[16];

    float* out = (float*)d_out;
    float* logits = out;                             // 64*32000
    float* h1 = out + 2048000;                       // 64*1024
    float* c1 = out + 2048000 + 65536;               // 64*1024
    float* wts = out + 2048000 + 65536 + 65536;      // 64*128

    // ws layout (floats):
    float* ws = (float*)d_ws;
    float* qp = ws;                        // 65536
    float* scores = ws + 65536;            // 8192   (qp+scores zeroed)
    float* xcat = ws + 73728;              // 196608
    float* gates_p = ws + 270336;          // 6*262144 = 1572864
    short* h1_bf = (short*)(ws + 1843200); // 65536 bf16
    short* encua_bf = (short*)(ws + 1908736);  // 9216*1024 bf16

    // 1. init: zero qp+scores, gather xcat[emb|..|h0]
    k_init<<<264, 256, 0, stream>>>(idx, emb, hidden, xcat, (float4*)ws);
    // 2. enc+Ua -> swizzled bf16
    k_cvt_swz<<<4608, 256, 0, stream>>>(enc, Ua_w, encua_bf);
    // 3. qp = h0 @ Wa^T (atomic; Wa_b folded into attn epilogue)
    k_sgemm<1><<<dim3(16, 8), 256, 0, stream>>>(hidden, 1024, Wa_w, 1024,
                                                nullptr, 0, 99, qp, 1024, 128, 0);
    // 4. attention scores (2-phase double-buffered)
    k_attn2<<<dim3(8, 32), 512, 0, stream>>>(encua_bf, encua_bf, Ua_b, Wa_b,
                                             qp, Va_w, scores);
    // 5. softmax + context
    k_smctx<<<64, 256, 0, stream>>>(scores, enc, wts, xcat);
    // 6. gates partials: xcat @ [W_ih|W_hh]^T, 6 K-splits of 512, stores
    k_sgemm<0><<<dim3(64, 6), 256, 0, stream>>>(xcat, 3072, W_ih, 2048,
                                                W_hh, 1024, 4, gates_p, 4096, 512, 262144);
    // 7. LSTM (sums 6 partials + biases), also writes h1 as bf16
    k_lstm6<<<256, 256, 0, stream>>>(gates_p, cell, b_ih, b_hh, h1, c1, h1_bf);
    // 8. logits = h1 @ out_w^T + out_b  (barrier-free streaming GEMM)
    k_vgemm<<<500, 256, 0, stream>>>(h1_bf, out_w, out_b, logits);
}

// Round 14
// 130.010 us; speedup vs baseline: 2.3023x; 1.0695x over previous
//
#include <hip/hip_runtime.h>
#include <hip/hip_bf16.h>

using short8 = __attribute__((ext_vector_type(8))) short;
using short4v = __attribute__((ext_vector_type(4))) short;
using f32x4  = __attribute__((ext_vector_type(4))) float;

__device__ inline unsigned pk2(float lo, float hi) {
    __hip_bfloat162 h = __float22bfloat162_rn(float2{lo, hi});
    return *reinterpret_cast<unsigned*>(&h);
}
__device__ inline short8 cvt8(float4 a, float4 b) {
    union { unsigned u[4]; short8 s; } r;
    r.u[0] = pk2(a.x, a.y); r.u[1] = pk2(a.z, a.w);
    r.u[2] = pk2(b.x, b.y); r.u[3] = pk2(b.z, b.w);
    return r.s;
}
__device__ inline float ftanh(float x) {
    float e = __expf(2.f * x);
    return 1.f - 2.f / (e + 1.f);
}
__device__ inline void gload16(const void* g, void* lds) {
    __builtin_amdgcn_global_load_lds(
        (const __attribute__((address_space(1))) unsigned int*)g,
        (__attribute__((address_space(3))) unsigned int*)lds, 16, 0, 0);
}
__device__ inline short f2b(float f) {
    unsigned u = __float_as_uint(f);
    return (short)((u + 0x7FFFu + ((u >> 16) & 1u)) >> 16);
}
__device__ inline float b2f(short s) {
    return __uint_as_float(((unsigned)(unsigned short)s) << 16);
}

// ---------------------------------------------------------------------------
// K1: fused [cvt+swizzle enc+Ua -> bf16 | zero qp+scores | xcat gather].
// Blocks [0,4608): cvt (elementwise). Blocks [4608,4872): init (elementwise).
// Both roles are low-register streaming code (no GEMM) -- codegen-safe fusion.
__global__ void k_prep(const float* __restrict__ enc, const float* __restrict__ Ua,
                       short* __restrict__ dst,
                       const int* __restrict__ idx, const float* __restrict__ emb,
                       const float* __restrict__ h0, float* __restrict__ xcat,
                       float4* __restrict__ wsz) {
    const int bid = blockIdx.x, t = threadIdx.x;
    if (bid < 4608) {
        // cvt role: dst[row][seg][g] = cvt(src[row][seg][g ^ (row&7)])
        int i = bid * 256 + t;  // < 9216*128 granules
        int row = i >> 7, gi = i & 127;
        int seg = gi >> 3, g = gi & 7;
        const float* src = (row < 8192) ? enc + ((size_t)row << 10)
                                        : Ua + ((size_t)(row - 8192) << 10);
        const float* p = src + (seg << 6) + ((g ^ (row & 7)) << 3);
        *(short8*)&dst[(size_t)i << 3] = cvt8(*(const float4*)p, *(const float4*)(p + 4));
    } else {
        int i = (bid - 4608) * 256 + t;
        if (i < 18432) {
            float4 z = {0.f, 0.f, 0.f, 0.f};
            wsz[i] = z;     // zero qp + scores
        } else if (i < 67584) {
            int j = i - 18432;
            int b = j / 768, q = j - b * 768;
            if (q < 256)
                ((float4*)(xcat + (size_t)b * 3072))[q] =
                    ((const float4*)(emb + (size_t)idx[b] * 1024))[q];
            else if (q >= 512)
                ((float4*)(xcat + (size_t)b * 3072))[q] =
                    ((const float4*)(h0 + (size_t)b * 1024))[q - 512];
        }
    }
}

// ---------------------------------------------------------------------------
// Attention-score GEMM, 256x128 tile, BK=64, global_load_lds, double-buffered.
// GRID IS (32 row-tiles, 8 col-tiles): linear bid = r + 32*c, so bid%8 = r%8
// -> all 8 col-blocks sharing A row-tile r land on the SAME XCD; the 512 KB
// A-tile becomes L2-resident instead of being re-fetched by 8 XCDs (was the
// 133 MB FETCH). 512 thr = 8 waves (4M x 2N). Fused tanh/Va epilogue.
__global__ __launch_bounds__(512) void k_attn2(
    const short* __restrict__ Abf, const short* __restrict__ Bbf,
    const float* __restrict__ Uab, const float* __restrict__ Wab,
    const float* __restrict__ qp, const float* __restrict__ Va,
    float* __restrict__ scores) {
    __shared__ short As[2][256 * 64];
    __shared__ short Bs[2][128 * 64];
    const int t = threadIdx.x;
    const int l = t & 63, w = t >> 6;
    const int wm = w >> 1, wn = w & 1;
    const int lr = l & 15, lg = l >> 4;
    const int r0 = blockIdx.x * 256;   // row tile  (32)
    const int n0 = blockIdx.y * 128;   // col tile  (8)

    f32x4 acc[4][4];
#pragma unroll
    for (int i = 0; i < 4; ++i)
#pragma unroll
        for (int j = 0; j < 4; ++j) { f32x4 z = {0.f, 0.f, 0.f, 0.f}; acc[i][j] = z; }

    auto STAGE = [&](int buf, int seg) {
#pragma unroll
        for (int i = 0; i < 4; ++i) {
            int base = i * 512 + w * 64;  // wave-uniform slot base
            int s = base + l;
            gload16(Abf + (((size_t)r0 + (s >> 3)) << 10) + (seg << 6) + ((s & 7) << 3),
                    (void*)&As[buf][base * 8]);
            if (i < 2)
                gload16(Bbf + (((size_t)8192 + n0 + (s >> 3)) << 10) + (seg << 6) + ((s & 7) << 3),
                        (void*)&Bs[buf][base * 8]);
        }
    };

    STAGE(0, 0);
    __syncthreads();

    for (int seg = 0; seg < 16; ++seg) {
        const int cur = seg & 1;
        if (seg < 15) STAGE(cur ^ 1, seg + 1);
#pragma unroll
        for (int kh = 0; kh < 2; ++kh) {
            short8 a[4], b[4];
#pragma unroll
            for (int i = 0; i < 4; ++i) {
                int ra = wm * 64 + i * 16 + lr;
                a[i] = *(const short8*)&As[cur][ra * 64 + (((kh * 4 + lg) ^ (ra & 7)) << 3)];
                int rb = wn * 64 + i * 16 + lr;
                b[i] = *(const short8*)&Bs[cur][rb * 64 + (((kh * 4 + lg) ^ (rb & 7)) << 3)];
            }
#pragma unroll
            for (int i = 0; i < 4; ++i)
#pragma unroll
                for (int j = 0; j < 4; ++j)
                    acc[i][j] = __builtin_amdgcn_mfma_f32_16x16x32_bf16(a[i], b[j], acc[i][j], 0, 0, 0);
        }
        __syncthreads();
    }

    float va[4], ub[4];
#pragma unroll
    for (int j = 0; j < 4; ++j) {
        int h = n0 + wn * 64 + j * 16 + lr;
        va[j] = Va[h];
        ub[j] = Uab[h] + Wab[h];
    }
#pragma unroll
    for (int i = 0; i < 4; ++i)
#pragma unroll
        for (int r = 0; r < 4; ++r) {
            int row = r0 + wm * 64 + i * 16 + lg * 4 + r;
            const float* qpb = qp + (size_t)(row >> 7) * 1024;
            float s = 0.f;
#pragma unroll
            for (int j = 0; j < 4; ++j) {
                int h = n0 + wn * 64 + j * 16 + lr;
                s += va[j] * ftanh(acc[i][j][r] + qpb[h] + ub[j]);
            }
            s += __shfl_xor(s, 1);
            s += __shfl_xor(s, 2);
            s += __shfl_xor(s, 4);
            s += __shfl_xor(s, 8);
            if (lr == 0) atomicAdd(scores + row, s);
        }
}

// ---------------------------------------------------------------------------
// Skinny split-K GEMM. EPI 1: atomicAdd into C (C pre-zeroed).
// EPI 0: store into partial buffer C + ky*pstride.
template <int EPI>
__global__ __launch_bounds__(256) void k_sgemm(
    const float* __restrict__ A, int lda,
    const float* __restrict__ B0, int ldb0,
    const float* __restrict__ B1, int ldb1, int kyB1,
    float* __restrict__ C, int ldc, int Kblk, int pstride) {
    __shared__ short As[64 * 64];
    __shared__ short Bs[64 * 64];
    const int t = threadIdx.x;
    const int l = t & 63, w = t >> 6;
    const int wm = w >> 1, wn = w & 1;
    const int lr = l & 15, lg = l >> 4;
    const int n0 = blockIdx.x * 64;
    const int ky = blockIdx.y;

    const float* Ab = A + (size_t)ky * Kblk;
    const float* Bb;
    int ldb;
    if (ky < kyB1) { Bb = B0 + (size_t)ky * Kblk; ldb = ldb0; }
    else           { Bb = B1 + (size_t)(ky - kyB1) * Kblk; ldb = ldb1; }

    f32x4 acc[2][2];
#pragma unroll
    for (int i = 0; i < 2; ++i)
#pragma unroll
        for (int j = 0; j < 2; ++j) { f32x4 z = {0.f, 0.f, 0.f, 0.f}; acc[i][j] = z; }

    for (int kt = 0; kt < Kblk; kt += 64) {
#pragma unroll
        for (int i = 0; i < 2; ++i) {
            int s = t + 256 * i, row = s >> 3, ch = s & 7;
            const float* p = Ab + (size_t)row * lda + kt + ch * 8;
            *(short8*)&As[row * 64 + ((ch ^ (row & 7)) << 3)] =
                cvt8(*(const float4*)p, *(const float4*)(p + 4));
            const float* q = Bb + (size_t)(n0 + row) * ldb + kt + ch * 8;
            *(short8*)&Bs[row * 64 + ((ch ^ (row & 7)) << 3)] =
                cvt8(*(const float4*)q, *(const float4*)(q + 4));
        }
        __syncthreads();
#pragma unroll
        for (int kh = 0; kh < 2; ++kh) {
            short8 a[2], b[2];
#pragma unroll
            for (int i = 0; i < 2; ++i) {
                int ra = wm * 32 + i * 16 + lr;
                a[i] = *(const short8*)&As[ra * 64 + (((kh * 4 + lg) ^ (ra & 7)) << 3)];
                int rb = wn * 32 + i * 16 + lr;
                b[i] = *(const short8*)&Bs[rb * 64 + (((kh * 4 + lg) ^ (rb & 7)) << 3)];
            }
#pragma unroll
            for (int i = 0; i < 2; ++i)
#pragma unroll
                for (int j = 0; j < 2; ++j)
                    acc[i][j] = __builtin_amdgcn_mfma_f32_16x16x32_bf16(a[i], b[j], acc[i][j], 0, 0, 0);
        }
        __syncthreads();
    }

    float* Cp = (EPI == 0) ? C + (size_t)ky * pstride : C;
#pragma unroll
    for (int i = 0; i < 2; ++i)
#pragma unroll
        for (int j = 0; j < 2; ++j)
#pragma unroll
            for (int r = 0; r < 4; ++r) {
                int R = wm * 32 + i * 16 + lg * 4 + r;
                int c = n0 + wn * 32 + j * 16 + lr;
                if constexpr (EPI == 1)
                    atomicAdd(&C[(size_t)R * ldc + c], acc[i][j][r]);
                else
                    Cp[(size_t)R * ldc + c] = acc[i][j][r];
            }
}

// ---------------------------------------------------------------------------
// Barrier-free streaming GEMM for logits: C(64 x 32000) = h1 @ out_w^T + b.
__global__ __launch_bounds__(256) void k_vgemm(
    const short* __restrict__ Abf, const float* __restrict__ B,
    const float* __restrict__ bias, float* __restrict__ C) {
    const int t = threadIdx.x;
    const int l = t & 63, w = t >> 6;
    const int lr = l & 15, lg = l >> 4;
    const int n0 = blockIdx.x * 64 + w * 16;

    f32x4 acc[4];
#pragma unroll
    for (int i = 0; i < 4; ++i) { f32x4 z = {0.f, 0.f, 0.f, 0.f}; acc[i] = z; }

    const float* bp = B + (size_t)(n0 + lr) * 1024 + lg * 8;
    const short* ap = Abf + lr * 1024 + lg * 8;

#pragma unroll 4
    for (int k0 = 0; k0 < 1024; k0 += 32) {
        float4 b0 = *(const float4*)(bp + k0);
        float4 b1 = *(const float4*)(bp + k0 + 4);
        short8 a0 = *(const short8*)(ap + k0);
        short8 a1 = *(const short8*)(ap + k0 + 16 * 1024);
        short8 a2 = *(const short8*)(ap + k0 + 32 * 1024);
        short8 a3 = *(const short8*)(ap + k0 + 48 * 1024);
        short8 bf = cvt8(b0, b1);
        acc[0] = __builtin_amdgcn_mfma_f32_16x16x32_bf16(a0, bf, acc[0], 0, 0, 0);
        acc[1] = __builtin_amdgcn_mfma_f32_16x16x32_bf16(a1, bf, acc[1], 0, 0, 0);
        acc[2] = __builtin_amdgcn_mfma_f32_16x16x32_bf16(a2, bf, acc[2], 0, 0, 0);
        acc[3] = __builtin_amdgcn_mfma_f32_16x16x32_bf16(a3, bf, acc[3], 0, 0, 0);
    }

    float bv = bias[n0 + lr];
#pragma unroll
    for (int i = 0; i < 4; ++i)
#pragma unroll
        for (int r = 0; r < 4; ++r)
            C[(size_t)(i * 16 + lg * 4 + r) * 32000 + n0 + lr] = acc[i][r] + bv;
}

// ---------------------------------------------------------------------------
// Fused softmax + context. Context reads enc_bf (bf16, 16 MB instead of
// 32 MB f32), un-XORing the granule swizzle (key = s&7 since rows per batch
// are a multiple of 8).
__global__ __launch_bounds__(256) void k_smctx(
    const float* __restrict__ scores, const short* __restrict__ enc_bf,
    float* __restrict__ wout, float* __restrict__ xcat) {
    int b = blockIdx.x;
    int t = threadIdx.x;
    __shared__ float buf[128];
    __shared__ float wsb[128];
    if (t < 128) buf[t] = scores[b * 128 + t];
    __syncthreads();
    if (t < 64) buf[t] = fmaxf(buf[t], buf[t + 64]);
    __syncthreads();
    if (t < 32) buf[t] = fmaxf(buf[t], buf[t + 32]);
    __syncthreads();
    float m;
    {
        float v = buf[t & 31];
        for (int off = 16; off > 0; off >>= 1)
            v = fmaxf(v, __shfl_xor(v, off, 32));
        m = v;
    }
    __syncthreads();
    if (t < 128) wsb[t] = __expf(scores[b * 128 + t] - m);
    __syncthreads();
    if (t < 64) buf[t] = wsb[t] + wsb[t + 64];
    __syncthreads();
    if (t < 32) buf[t] += buf[t + 32];
    __syncthreads();
    float sum;
    {
        float v = buf[t & 31];
        for (int off = 16; off > 0; off >>= 1)
            v += __shfl_xor(v, off, 32);
        sum = v;
    }
    float inv = 1.f / sum;
    __syncthreads();
    if (t < 128) {
        wsb[t] *= inv;
        wout[b * 128 + t] = wsb[t];
    }
    __syncthreads();
    // context from swizzled bf16: h = 4t; addr = (row<<10)+(seg<<6)+((g^(s&7))<<3)+e
    int h = t * 4;
    int seg = h >> 6, g = (h >> 3) & 7, e0 = h & 7;
    const short* basebf = enc_bf + (((size_t)b * 128) << 10) + (seg << 6) + e0;
    float a0 = 0.f, a1 = 0.f, a2 = 0.f, a3 = 0.f;
    for (int s = 0; s < 128; ++s) {
        float wv = wsb[s];
        const short* p = basebf + ((size_t)s << 10) + ((g ^ (s & 7)) << 3);
        short4v v = *(const short4v*)p;
        a0 += wv * b2f(v[0]);
        a1 += wv * b2f(v[1]);
        a2 += wv * b2f(v[2]);
        a3 += wv * b2f(v[3]);
    }
    float4 o = {a0, a1, a2, a3};
    *(float4*)&xcat[(size_t)b * 3072 + 1024 + h] = o;
}

// ---------------------------------------------------------------------------
// LSTM pointwise; sums 6 gate partials + biases; also emits h1 as bf16.
__global__ void k_lstm6(const float* __restrict__ gp, const float* __restrict__ c0,
                        const float* __restrict__ b_ih, const float* __restrict__ b_hh,
                        float* __restrict__ h1, float* __restrict__ c1,
                        short* __restrict__ h1bf) {
    int idx = blockIdx.x * blockDim.x + threadIdx.x;  // 65536
    int b = idx >> 10, h = idx & 1023;
    const float* g0 = gp + (size_t)b * 4096;
    float iv = b_ih[h] + b_hh[h];
    float fv = b_ih[1024 + h] + b_hh[1024 + h];
    float gv = b_ih[2048 + h] + b_hh[2048 + h];
    float ov = b_ih[3072 + h] + b_hh[3072 + h];
#pragma unroll
    for (int p = 0; p < 6; ++p) {
        const float* g = g0 + p * 262144;
        iv += g[h];
        fv += g[1024 + h];
        gv += g[2048 + h];
        ov += g[3072 + h];
    }
    float si = 1.f / (1.f + expf(-iv));
    float sf = 1.f / (1.f + expf(-fv));
    float so = 1.f / (1.f + expf(-ov));
    float tg = tanhf(gv);
    float cc = sf * c0[idx] + si * tg;
    float hh = so * tanhf(cc);
    c1[idx] = cc;
    h1[idx] = hh;
    h1bf[idx] = f2b(hh);
}

// ---------------------------------------------------------------------------
extern "C" void kernel_launch(void* const* d_in, const int* in_sizes, int n_in,
                              void* d_out, int out_size, void* d_ws, size_t ws_size,
                              hipStream_t stream) {
    const int* idx = (const int*)d_in[0];
    const float* hidden = (const float*)d_in[1];
    const float* cell = (const float*)d_in[2];
    const float* enc = (const float*)d_in[3];
    const float* emb = (const float*)d_in[4];
    const float* Wa_w = (const float*)d_in[5];
    const float* Wa_b = (const float*)d_in[6];
    const float* Ua_w = (const float*)d_in[7];
    const float* Ua_b = (const float*)d_in[8];
    const float* Va_w = (const float*)d_in[9];
    // d_in[10] Va_b unused: softmax shift-invariant
    const float* W_ih = (const float*)d_in[11];
    const float* W_hh = (const float*)d_in[12];
    const float* b_ih = (const float*)d_in[13];
    const float* b_hh = (const float*)d_in[14];
    const float* out_w = (const float*)d_in[15];
    const float* out_b = (const float*)d_in[16];

    float* out = (float*)d_out;
    float* logits = out;                             // 64*32000
    float* h1 = out + 2048000;                       // 64*1024
    float* c1 = out + 2048000 + 65536;               // 64*1024
    float* wts = out + 2048000 + 65536 + 65536;      // 64*128

    // ws layout (floats):
    float* ws = (float*)d_ws;
    float* qp = ws;                        // 65536
    float* scores = ws + 65536;            // 8192   (qp+scores zeroed)
    float* xcat = ws + 73728;              // 196608
    float* gates_p = ws + 270336;          // 6*262144 = 1572864
    short* h1_bf = (short*)(ws + 1843200); // 65536 bf16
    short* encua_bf = (short*)(ws + 1908736);  // 9216*1024 bf16

    // 1. prep: cvt enc+Ua -> bf16 | zero qp+scores | xcat gather
    k_prep<<<4872, 256, 0, stream>>>(enc, Ua_w, encua_bf, idx, emb, hidden,
                                     xcat, (float4*)ws);
    // 2. qp = h0 @ Wa^T (atomic; Wa_b folded into attn epilogue)
    k_sgemm<1><<<dim3(16, 8), 256, 0, stream>>>(hidden, 1024, Wa_w, 1024,
                                                nullptr, 0, 99, qp, 1024, 128, 0);
    // 3. attention scores (XCD-friendly transposed grid: rows fast)
    k_attn2<<<dim3(32, 8), 512, 0, stream>>>(encua_bf, encua_bf, Ua_b, Wa_b,
                                             qp, Va_w, scores);
    // 4. softmax + context (reads bf16 enc)
    k_smctx<<<64, 256, 0, stream>>>(scores, encua_bf, wts, xcat);
    // 5. gates partials: xcat @ [W_ih|W_hh]^T, 6 K-splits of 512, stores
    k_sgemm<0><<<dim3(64, 6), 256, 0, stream>>>(xcat, 3072, W_ih, 2048,
                                                W_hh, 1024, 4, gates_p, 4096, 512, 262144);
    // 6. LSTM (sums 6 partials + biases), also writes h1 as bf16
    k_lstm6<<<256, 256, 0, stream>>>(gates_p, cell, b_ih, b_hh, h1, c1, h1_bf);
    // 7. logits = h1 @ out_w^T + out_b  (barrier-free streaming GEMM)
    k_vgemm<<<500, 256, 0, stream>>>(h1_bf, out_w, out_b, logits);
}